// Round 13
// baseline (260.281 us; speedup 1.0000x reference)
//
#include <hip/hip_runtime.h>
#include <hip/hip_bf16.h>

// GCN: 3 x [ relu(A @ (X @ W) + b) ]  (no relu layer 3), fp32 I/O, bf16 MFMA.
// R12: G2f rebuilt — adj staged AS F32 via global_load_lds (A f32 dbuf 128KB),
// fragments converted on read with v_cvt_pk_bf16_f32; B single 32KB buffer;
// adjb writeback from LDS at ph2 (after stageB) so ph3 counted vmcnt lets wb
// stores fly. No ds_write / no reg-staging anywhere in G2f (m151 tax removed).
//   G1: T  = W^T @ X^T : gemm(A=WT [F][F], BT=X [N][F]) -> T [F][N]
//   G2: X' = adj @ T^T : gemm(A=adj [N][N], BT=T [F][N]) -> X' [N][F] (+b,relu)
// G1f (R11), gemm256 (R8 core), prep: unchanged.

typedef __attribute__((ext_vector_type(8))) short bf16x8s;
typedef __attribute__((ext_vector_type(4))) float f32x4;
typedef __attribute__((ext_vector_type(4))) unsigned short us4;
typedef __attribute__((ext_vector_type(8))) unsigned short us8;

__device__ __forceinline__ unsigned short f2bf(float f) {
    unsigned u = __builtin_bit_cast(unsigned, f);
    u += 0x7fffu + ((u >> 16) & 1u);          // RNE
    return (unsigned short)(u >> 16);
}

__device__ __forceinline__ us8 pack8(float4 a, float4 b) {
    us8 o;
    o[0] = f2bf(a.x); o[1] = f2bf(a.y); o[2] = f2bf(a.z); o[3] = f2bf(a.w);
    o[4] = f2bf(b.x); o[5] = f2bf(b.y); o[6] = f2bf(b.z); o[7] = f2bf(b.w);
    return o;
}

// 8 f32 -> 8 bf16 via packed cvt (RNE on gfx950)
__device__ __forceinline__ bf16x8s cvt8(float4 a, float4 b) {
    int4 r;
    asm("v_cvt_pk_bf16_f32 %0, %1, %2" : "=v"(r.x) : "v"(a.x), "v"(a.y));
    asm("v_cvt_pk_bf16_f32 %0, %1, %2" : "=v"(r.y) : "v"(a.z), "v"(a.w));
    asm("v_cvt_pk_bf16_f32 %0, %1, %2" : "=v"(r.z) : "v"(b.x), "v"(b.y));
    asm("v_cvt_pk_bf16_f32 %0, %1, %2" : "=v"(r.w) : "v"(b.z), "v"(b.w));
    return __builtin_bit_cast(bf16x8s, r);
}
__device__ __forceinline__ us4 cvt4(float4 a) {
    int2 r;
    asm("v_cvt_pk_bf16_f32 %0, %1, %2" : "=v"(r.x) : "v"(a.x), "v"(a.y));
    asm("v_cvt_pk_bf16_f32 %0, %1, %2" : "=v"(r.y) : "v"(a.z), "v"(a.w));
    return __builtin_bit_cast(us4, r);
}

__device__ __forceinline__ void async16(const unsigned short* g, unsigned short* l) {
    __builtin_amdgcn_global_load_lds(
        (const __attribute__((address_space(1))) unsigned int*)g,
        (__attribute__((address_space(3))) unsigned int*)l, 16, 0, 0);
}

#define MFMA_(d, va, vb) d = __builtin_amdgcn_mfma_f32_16x16x32_bf16(va, vb, d, 0, 0, 0)

// -------- prep: three W transposes only (3 MB) --------
__global__ void prep(const float* __restrict__ W1, const float* __restrict__ W2,
                     const float* __restrict__ W3, unsigned short* __restrict__ WT1,
                     unsigned short* __restrict__ WT2, unsigned short* __restrict__ WT3) {
    constexpr int F = 512;
    const long FF = (long)F * F;
    const long S = (long)gridDim.x * 256;
    for (long k = (long)blockIdx.x * 256 + threadIdx.x; k < 3 * FF; k += S) {
        int w = (int)(k / FF);
        long idx = k % FF;
        int r = (int)(idx % F);
        int c = (int)(idx / F);
        const float* W = (w == 0) ? W1 : (w == 1) ? W2 : W3;
        unsigned short* WT = (w == 0) ? WT1 : (w == 1) ? WT2 : WT3;
        WT[idx] = f2bf(W[(size_t)r * F + c]);
    }
}

// ================= fused G1 layer-1: PT = WT1 @ X0^T (X0 = f32) =============
__global__ __launch_bounds__(512, 2)
void gemm_g1f(const unsigned short* __restrict__ WT,   // [512][512] bf16
              const float* __restrict__ X0,            // [32][1024][512] f32
              unsigned short* __restrict__ PT)         // [32][512][1024] bf16
{
    constexpr int K = 512, NN = 1024;
    constexpr int nt = K >> 6;                          // 8
    __shared__ unsigned short Lraw[65536];              // A dbuf 64KB | B dbuf 64KB

    const int t = threadIdx.x, lane = t & 63, wv = t >> 6;
    const int wm = wv >> 2, wn = wv & 3;
    const int fr = lane & 15, fk = (lane >> 4) * 8, r4 = (lane >> 4) * 4;
    const int lb = ((int)blockIdx.x & 7) * 32 + ((int)blockIdx.x >> 3);
    const int bat = lb >> 3, tt = lb & 7;
    const int m0 = (tt >> 2) << 8, n0 = (tt & 3) << 8;  // 2 M-tiles x 4 N-tiles

    const unsigned short* Ab = WT + (size_t)m0 * K;
    const float* Bb = X0 + (size_t)bat * NN * K + (size_t)n0 * K;

    int srow[2], scol[2], lo[2];
#pragma unroll
    for (int r = 0; r < 2; ++r) {
        int c   = r * 512 + t;
        srow[r] = c >> 3;
        scol[r] = ((c & 7) * 8) ^ ((srow[r] & 7) << 3);
        lo[r]   = c * 8;
    }

    auto stageA = [&](int kt, int h) {
        unsigned short* base = Lraw + (kt & 1) * 16384;
#pragma unroll
        for (int r = 0; r < 2; ++r)
            async16(Ab + (size_t)(h * 128 + srow[r]) * K + kt * 64 + scol[r],
                    base + h * 8192 + lo[r]);
    };
    auto rdA = [&](int buf, int mf, int kkj) -> bf16x8s {
        int row = wm * 128 + mf * 16 + fr;
        int e   = (kkj * 32 + fk) ^ ((row & 7) << 3);
        return *(const bf16x8s*)&Lraw[buf * 16384 + row * 64 + e];
    };
    auto rdB = [&](int buf, int nf, int kkj) -> bf16x8s {
        int row = wn * 64 + nf * 16 + fr;
        int e   = (kkj * 32 + fk) ^ ((row & 7) << 3);
        return *(const bf16x8s*)&Lraw[32768 + buf * 16384 + row * 64 + e];
    };

    float4 fa[4], fb[4];
    auto loadB = [&](int kt) {
#pragma unroll
        for (int h = 0; h < 2; ++h)
#pragma unroll
            for (int r = 0; r < 2; ++r) {
                const float* p = Bb + (size_t)(h * 128 + srow[r]) * K + kt * 64 + scol[r];
                fa[h * 2 + r] = *(const float4*)p;
                fb[h * 2 + r] = *(const float4*)(p + 4);
            }
    };
    auto writeB = [&](int buf) {
#pragma unroll
        for (int h = 0; h < 2; ++h)
#pragma unroll
            for (int r = 0; r < 2; ++r)
                *(us8*)&Lraw[32768 + buf * 16384 + h * 8192 + lo[r]] =
                    pack8(fa[h * 2 + r], fb[h * 2 + r]);
    };

    f32x4 acc[8][4];
#pragma unroll
    for (int i = 0; i < 8; ++i)
#pragma unroll
        for (int j = 0; j < 4; ++j) acc[i][j] = f32x4{0.f, 0.f, 0.f, 0.f};
    bf16x8s aP[4], aB[4], aC[4], bX[4], bY[4];

    loadB(0);
    stageA(0, 0); stageA(0, 1);
    writeB(0);
    loadB(1);
    asm volatile("s_waitcnt vmcnt(8)" ::: "memory");
    __syncthreads();
#pragma unroll
    for (int m = 0; m < 4; ++m) aP[m] = rdA(0, m, 0);
#pragma unroll
    for (int n = 0; n < 4; ++n) bX[n] = rdB(0, n, 0);

    for (int it = 0; it < nt; ++it) {
        const int cur = it & 1, nxt = cur ^ 1;
        const bool m1 = it + 1 < nt, m2 = it + 2 < nt;

        __builtin_amdgcn_s_barrier();                       // ph0
#pragma unroll
        for (int m = 0; m < 4; ++m) aB[m] = rdA(cur, m + 4, 0);
        if (m1) { stageA(it + 1, 0); stageA(it + 1, 1); }
        __builtin_amdgcn_s_setprio(1);
#pragma unroll
        for (int m = 0; m < 4; ++m)
#pragma unroll
            for (int n = 0; n < 4; ++n) MFMA_(acc[m][n], aP[m], bX[n]);
        __builtin_amdgcn_s_setprio(0);

        __builtin_amdgcn_s_barrier();                       // ph1
#pragma unroll
        for (int m = 0; m < 4; ++m) aC[m] = rdA(cur, m, 1);
#pragma unroll
        for (int n = 0; n < 4; ++n) bY[n] = rdB(cur, n, 1);
        __builtin_amdgcn_s_setprio(1);
#pragma unroll
        for (int m = 0; m < 4; ++m)
#pragma unroll
            for (int n = 0; n < 4; ++n) MFMA_(acc[m + 4][n], aB[m], bX[n]);
        __builtin_amdgcn_s_setprio(0);

        __builtin_amdgcn_s_barrier();                       // ph2
#pragma unroll
        for (int m = 0; m < 4; ++m) aB[m] = rdA(cur, m + 4, 1);
        if (m1) writeB(nxt);
        if (m2) loadB(it + 2);
        __builtin_amdgcn_s_setprio(1);
#pragma unroll
        for (int m = 0; m < 4; ++m)
#pragma unroll
            for (int n = 0; n < 4; ++n) MFMA_(acc[m][n], aC[m], bY[n]);
        __builtin_amdgcn_s_setprio(0);

        if (m1) {                                           // ph3
            if (m2) asm volatile("s_waitcnt vmcnt(8) lgkmcnt(0)" ::: "memory");
            else    asm volatile("s_waitcnt vmcnt(0) lgkmcnt(0)" ::: "memory");
            __builtin_amdgcn_s_barrier();
#pragma unroll
            for (int m = 0; m < 4; ++m) aP[m] = rdA(nxt, m, 0);
#pragma unroll
            for (int n = 0; n < 4; ++n) bX[n] = rdB(nxt, n, 0);
        }
        __builtin_amdgcn_s_setprio(1);
#pragma unroll
        for (int m = 0; m < 4; ++m)
#pragma unroll
            for (int n = 0; n < 4; ++n) MFMA_(acc[m + 4][n], aB[m], bY[n]);
        __builtin_amdgcn_s_setprio(0);
    }

    __syncthreads();
    const int R0 = m0 + wm * 128;
    const int C0 = n0 + wn * 64;
    unsigned short* sl = Lraw + wv * 8192;
#pragma unroll
    for (int i = 0; i < 8; ++i)
#pragma unroll
        for (int j = 0; j < 4; ++j)
#pragma unroll
            for (int e = 0; e < 4; ++e) {
                const int row = i * 16 + r4 + e;
                const int col = j * 16 + fr;
                sl[row * 64 + (col ^ ((row & 7) << 3))] = f2bf(acc[i][j][e]);
            }
    unsigned short* Cb = PT + (size_t)bat * 512 * 1024;
#pragma unroll
    for (int rr = 0; rr < 16; ++rr) {
        const int row = rr * 8 + (lane >> 3);
        const int k8  = lane & 7;
        us8 v = *(const us8*)&sl[row * 64 + ((k8 ^ (row & 7)) << 3)];
        *(us8*)&Cb[(size_t)(R0 + row) * NN + C0 + k8 * 8] = v;
    }
}

// ====== fused G2 layer-1: P1 = relu(adj @ PT^T + b1) ========================
// A = adj staged AS F32 via async16 (dbuf 2x64KB); frags cvt_pk'd on read.
// B = PT bf16, single 32KB buffer. adjb writeback from LDS (n0==0 blocks).
__global__ __launch_bounds__(512, 2)
void gemm_g2f(const float* __restrict__ ADJ,            // [32][1024][1024] f32
              unsigned short* __restrict__ adjb,        // bf16 out (plain layout)
              const unsigned short* __restrict__ PT,    // [32][512][1024] bf16
              unsigned short* __restrict__ P1,          // [32][1024][512] bf16
              const float* __restrict__ bias)
{
    constexpr int K = 1024, NN = 512;
    constexpr int nt = K >> 6;                          // 16
    __shared__ float Af[2][16384];                      // 2 x 64 KB (f32 tiles)
    __shared__ unsigned short Bl[16384];                // 32 KB  (total 160 KB)

    const int t = threadIdx.x, lane = t & 63, wv = t >> 6;
    const int wm = wv >> 2, wn = wv & 3;
    const int fr = lane & 15, fk = (lane >> 4) * 8, r4 = (lane >> 4) * 4;
    const int lb = ((int)blockIdx.x & 7) * 32 + ((int)blockIdx.x >> 3);
    const int bat = lb >> 3, tt = lb & 7;
    const int m0 = (tt >> 1) << 8, n0 = (tt & 1) << 8;  // 4 M-tiles x 2 N-tiles
    const bool wb = (n0 == 0);

    const float* Afb = ADJ + (size_t)bat * K * K + (size_t)m0 * K;
    unsigned short* Awb = adjb + (size_t)bat * K * K + (size_t)m0 * K;
    const unsigned short* Bb = PT + (size_t)bat * NN * K + (size_t)n0 * K;

    // B staging map (bf16 chunk swizzle, as proven)
    int srow[2], scol[2], lo[2];
#pragma unroll
    for (int r = 0; r < 2; ++r) {
        int c   = r * 512 + t;
        srow[r] = c >> 3;
        scol[r] = ((c & 7) * 8) ^ ((srow[r] & 7) << 3);
        lo[r]   = c * 8;
    }
    auto stageB = [&](int kt) {                         // 4 asyncs
#pragma unroll
        for (int h = 0; h < 2; ++h)
#pragma unroll
            for (int r = 0; r < 2; ++r)
                async16(Bb + (size_t)(h * 128 + srow[r]) * K + kt * 64 + scol[r],
                        Bl + h * 8192 + lo[r]);
    };
    auto rdB = [&](int nf, int kkj) -> bf16x8s {
        int row = wn * 64 + nf * 16 + fr;
        int e   = (kkj * 32 + fk) ^ ((row & 7) << 3);
        return *(const bf16x8s*)&Bl[row * 64 + e];
    };

    // A f32 staging: 16B-unit swizzle u ^= (row&15); linear LDS dest.
    // unit c = q*512+t : row=c>>4, u=c&15 ; 8 units/thread per tile.
    auto stageAf = [&](int kt, int half) {              // 4 asyncs per half
#pragma unroll
        for (int q = half * 4; q < half * 4 + 4; ++q) {
            int c   = q * 512 + t;
            int row = c >> 4;
            int us  = (c & 15) ^ (row & 15);
            async16((const unsigned short*)(Afb + (size_t)row * K + kt * 64 + us * 4),
                    (unsigned short*)&Af[kt & 1][(size_t)c * 4]);
        }
    };
    auto rdAf = [&](int buf, int mf, int kkj) -> bf16x8s {
        int row = wm * 128 + mf * 16 + fr;
        int u   = (kkj * 32 + fk) >> 2;                 // even 16B-unit
        int r15 = row & 15;
        float4 a = *(const float4*)&Af[buf][row * 64 + ((u ^ r15) << 2)];
        float4 b = *(const float4*)&Af[buf][row * 64 + (((u + 1) ^ r15) << 2)];
        return cvt8(a, b);
    };
    auto wbTile = [&](int buf, int kt) {                // LDS f32 -> bf16 global
#pragma unroll
        for (int q = 0; q < 8; ++q) {
            int c   = q * 512 + t;
            int row = c >> 4;
            int us  = (c & 15) ^ (row & 15);
            float4 v = *(const float4*)&Af[buf][(size_t)c * 4];
            *(us4*)&Awb[(size_t)row * K + kt * 64 + us * 4] = cvt4(v);
        }
    };

    f32x4 acc[8][4];
#pragma unroll
    for (int i = 0; i < 8; ++i)
#pragma unroll
        for (int j = 0; j < 4; ++j) acc[i][j] = f32x4{0.f, 0.f, 0.f, 0.f};
    bf16x8s aP[4], aB[4], aC[4], bX[4], bY[4];

    // prologue: A(0) f32 + B(0)
    stageAf(0, 0); stageAf(0, 1);
    stageB(0);
    asm volatile("s_waitcnt vmcnt(0)" ::: "memory");
    __syncthreads();
#pragma unroll
    for (int m = 0; m < 4; ++m) aP[m] = rdAf(0, m, 0);
#pragma unroll
    for (int n = 0; n < 4; ++n) bX[n] = rdB(n, 0);

    for (int it = 0; it < nt; ++it) {
        const int cur = it & 1, nxt = cur ^ 1;
        const bool m1 = it + 1 < nt;

        __builtin_amdgcn_s_barrier();                       // ph0
#pragma unroll
        for (int m = 0; m < 4; ++m) aB[m] = rdAf(cur, m + 4, 0);
#pragma unroll
        for (int n = 0; n < 4; ++n) bY[n] = rdB(n, 1);      // frees B buffer
        if (m1) stageAf(it + 1, 0);                         // 4 asyncs
        __builtin_amdgcn_s_setprio(1);
#pragma unroll
        for (int m = 0; m < 4; ++m)
#pragma unroll
            for (int n = 0; n < 4; ++n) MFMA_(acc[m][n], aP[m], bX[n]);
        __builtin_amdgcn_s_setprio(0);

        __builtin_amdgcn_s_barrier();                       // ph1
#pragma unroll
        for (int m = 0; m < 4; ++m) aC[m] = rdAf(cur, m, 1);
        if (m1) { stageAf(it + 1, 1); stageB(it + 1); }     // 4 + 4 asyncs
        __builtin_amdgcn_s_setprio(1);
#pragma unroll
        for (int m = 0; m < 4; ++m)
#pragma unroll
            for (int n = 0; n < 4; ++n) MFMA_(acc[m + 4][n], aB[m], bX[n]);
        __builtin_amdgcn_s_setprio(0);

        __builtin_amdgcn_s_barrier();                       // ph2
#pragma unroll
        for (int m = 0; m < 4; ++m) aB[m] = rdAf(cur, m + 4, 1);
        if (wb) wbTile(cur, it);                            // 8 x 8B stores (newest)
        __builtin_amdgcn_s_setprio(1);
#pragma unroll
        for (int m = 0; m < 4; ++m)
#pragma unroll
            for (int n = 0; n < 4; ++n) MFMA_(acc[m][n], aC[m], bY[n]);
        __builtin_amdgcn_s_setprio(0);

        if (m1) {                                           // ph3
            // queue: Af(it+1)[8] + B(it+1)[4] older than wb stores[8]
            if (wb) asm volatile("s_waitcnt vmcnt(8)" ::: "memory");
            else    asm volatile("s_waitcnt vmcnt(0)" ::: "memory");
            __builtin_amdgcn_s_barrier();
#pragma unroll
            for (int m = 0; m < 4; ++m) aP[m] = rdAf(nxt, m, 0);
#pragma unroll
            for (int n = 0; n < 4; ++n) bX[n] = rdB(n, 0);
        }
        __builtin_amdgcn_s_setprio(1);
#pragma unroll
        for (int m = 0; m < 4; ++m)
#pragma unroll
            for (int n = 0; n < 4; ++n) MFMA_(acc[m + 4][n], aB[m], bY[n]);
        __builtin_amdgcn_s_setprio(0);
    }

    __syncthreads();
    // epilogue: bias + relu, LDS bounce (reuse Af area), P1 row-major
    const int R0 = m0 + wm * 128;
    const int C0 = n0 + wn * 64;
    float bv[4];
#pragma unroll
    for (int j = 0; j < 4; ++j) bv[j] = bias[C0 + j * 16 + fr];
    unsigned short* sl = (unsigned short*)Af + wv * 8192;
#pragma unroll
    for (int i = 0; i < 8; ++i)
#pragma unroll
        for (int j = 0; j < 4; ++j)
#pragma unroll
            for (int e = 0; e < 4; ++e) {
                const int row = i * 16 + r4 + e;
                const int col = j * 16 + fr;
                sl[row * 64 + (col ^ ((row & 7) << 3))] =
                    f2bf(fmaxf(acc[i][j][e] + bv[j], 0.f));
            }
    __syncthreads();
    unsigned short* Cb = P1 + (size_t)bat * 1024 * 512;
#pragma unroll
    for (int rr = 0; rr < 16; ++rr) {
        const int row = rr * 8 + (lane >> 3);
        const int k8  = lane & 7;
        us8 v = *(const us8*)&sl[row * 64 + ((k8 ^ (row & 7)) << 3)];
        *(us8*)&Cb[(size_t)(R0 + row) * NN + C0 + k8 * 8] = v;
    }
}

// ================= R8 core (unchanged) for the 4 bf16 GEMMs =================
template<bool RELU, bool OUT_F32>
__global__ __launch_bounds__(512, 2)
void gemm256(const unsigned short* __restrict__ A,
             const unsigned short* __restrict__ BT,
             void* __restrict__ Cout,
             const float* __restrict__ bias,
             int M, int N, int K,
             long sA, long sBT, long sC)
{
    __shared__ unsigned short Lraw[81920];

    const int t    = threadIdx.x;
    const int lane = t & 63;
    const int wv   = t >> 6;
    const int wm   = wv >> 2;
    const int wn   = wv & 3;
    const int fr   = lane & 15;
    const int fk   = (lane >> 4) * 8;
    const int r4   = (lane >> 4) * 4;

    const int tilesN = N >> 8;
    const int bpb    = (M >> 8) * tilesN;
    const int cpx = gridDim.x >> 3;
    const int lb  = (blockIdx.x & 7) * cpx + (blockIdx.x >> 3);
    const int bat = lb / bpb;
    const int tt  = lb % bpb;
    const int m0  = (tt / tilesN) << 8;
    const int n0  = (tt % tilesN) << 8;

    const unsigned short* Ab = A  + (size_t)bat * sA  + (size_t)m0 * K;
    const unsigned short* Bb = BT + (size_t)bat * sBT + (size_t)n0 * K;

    int srow[2], scol[2], lo[2];
#pragma unroll
    for (int r = 0; r < 2; ++r) {
        int c   = r * 512 + t;
        srow[r] = c >> 3;
        scol[r] = ((c & 7) * 8) ^ ((srow[r] & 7) << 3);
        lo[r]   = c * 8;
    }

    auto stageA = [&](int kt, int h) {
        unsigned short* base = Lraw + (kt & 1) * 16384;
#pragma unroll
        for (int r = 0; r < 2; ++r)
            async16(Ab + (size_t)(h * 128 + srow[r]) * K + kt * 64 + scol[r],
                    base + h * 8192 + lo[r]);
    };
    auto stageB = [&](int buf, int kt) {
        unsigned short* base = Lraw + 32768 + buf * 16384;
#pragma unroll
        for (int h = 0; h < 2; ++h)
#pragma unroll
            for (int r = 0; r < 2; ++r)
                async16(Bb + (size_t)(h * 128 + srow[r]) * K + kt * 64 + scol[r],
                        base + h * 8192 + lo[r]);
    };
    auto rdA = [&](int buf, int mf, int kkj) -> bf16x8s {
        int row = wm * 128 + mf * 16 + fr;
        int e   = (kkj * 32 + fk) ^ ((row & 7) << 3);
        return *(const bf16x8s*)&Lraw[buf * 16384 + row * 64 + e];
    };
    auto rdB = [&](int buf, int nf, int kkj) -> bf16x8s {
        int row = wn * 64 + nf * 16 + fr;
        int e   = (kkj * 32 + fk) ^ ((row & 7) << 3);
        return *(const bf16x8s*)&Lraw[32768 + buf * 16384 + row * 64 + e];
    };

    const int nt = K >> 6;

    f32x4 acc[8][4];
#pragma unroll
    for (int i = 0; i < 8; ++i)
#pragma unroll
        for (int j = 0; j < 4; ++j) acc[i][j] = f32x4{0.f, 0.f, 0.f, 0.f};

    bf16x8s aP[4], aB[4], aC[4], bX[4], bY[4];

    stageA(0, 0); stageA(0, 1);
    stageB(0, 0);
    if (nt > 1) {
        stageB(1, 1);
        asm volatile("s_waitcnt vmcnt(4)" ::: "memory");
    } else {
        asm volatile("s_waitcnt vmcnt(0)" ::: "memory");
    }
    __builtin_amdgcn_s_barrier();
#pragma unroll
    for (int m = 0; m < 4; ++m) aP[m] = rdA(0, m, 0);
#pragma unroll
    for (int n = 0; n < 4; ++n) bX[n] = rdB(0, n, 0);

    int bc = 0;
    for (int it = 0; it < nt; ++it) {
        const int cur = it & 1;
        const int bn1 = (bc == 2) ? 0 : bc + 1;
        const int bn2 = (bn1 == 2) ? 0 : bn1 + 1;
        const bool m1 = (it + 1 < nt), m2 = (it + 2 < nt);

        __builtin_amdgcn_s_barrier();
#pragma unroll
        for (int m = 0; m < 4; ++m) aB[m] = rdA(cur, m + 4, 0);
        if (m1) stageA(it + 1, 0);
        __builtin_amdgcn_s_setprio(1);
#pragma unroll
        for (int m = 0; m < 4; ++m)
#pragma unroll
            for (int n = 0; n < 4; ++n) MFMA_(acc[m][n], aP[m], bX[n]);
        __builtin_amdgcn_s_setprio(0);

        __builtin_amdgcn_s_barrier();
#pragma unroll
        for (int m = 0; m < 4; ++m) aC[m] = rdA(cur, m, 1);
#pragma unroll
        for (int n = 0; n < 4; ++n) bY[n] = rdB(bc, n, 1);
        if (m1) stageA(it + 1, 1);
        __builtin_amdgcn_s_setprio(1);
#pragma unroll
        for (int m = 0; m < 4; ++m)
#pragma unroll
            for (int n = 0; n < 4; ++n) MFMA_(acc[m + 4][n], aB[m], bX[n]);
        __builtin_amdgcn_s_setprio(0);

        __builtin_amdgcn_s_barrier();
#pragma unroll
        for (int m = 0; m < 4; ++m) aB[m] = rdA(cur, m + 4, 1);
        if (m2) stageB(bn2, it + 2);
        __builtin_amdgcn_s_setprio(1);
#pragma unroll
        for (int m = 0; m < 4; ++m)
#pragma unroll
            for (int n = 0; n < 4; ++n) MFMA_(acc[m][n], aC[m], bY[n]);
        __builtin_amdgcn_s_setprio(0);

        if (m1) {
            if (m2) asm volatile("s_waitcnt vmcnt(4)" ::: "memory");
            else    asm volatile("s_waitcnt vmcnt(0)" ::: "memory");
            __builtin_amdgcn_s_barrier();
#pragma unroll
            for (int m = 0; m < 4; ++m) aP[m] = rdA(cur ^ 1, m, 0);
#pragma unroll
            for (int n = 0; n < 4; ++n) bX[n] = rdB(bn1, n, 0);
        }
        __builtin_amdgcn_s_setprio(1);
#pragma unroll
        for (int m = 0; m < 4; ++m)
#pragma unroll
            for (int n = 0; n < 4; ++n) MFMA_(acc[m + 4][n], aB[m], bY[n]);
        __builtin_amdgcn_s_setprio(0);
        bc = bn1;
    }

    __syncthreads();

    const int R0 = m0 + wm * 128;
    const int C0 = n0 + wn * 64;
    float bv[4];
#pragma unroll
    for (int j = 0; j < 4; ++j)
        bv[j] = bias ? bias[C0 + j * 16 + fr] : 0.f;

    if (OUT_F32) {
        float* Cb = (float*)Cout + (size_t)bat * sC;
#pragma unroll
        for (int j = 0; j < 4; ++j)
#pragma unroll
            for (int i = 0; i < 8; ++i)
#pragma unroll
                for (int e = 0; e < 4; ++e) {
                    float v = acc[i][j][e] + bv[j];
                    if (RELU) v = fmaxf(v, 0.f);
                    Cb[(size_t)(R0 + i * 16 + r4 + e) * N + C0 + j * 16 + fr] = v;
                }
    } else {
        unsigned short* sl = Lraw + wv * 8192;
#pragma unroll
        for (int i = 0; i < 8; ++i)
#pragma unroll
            for (int j = 0; j < 4; ++j)
#pragma unroll
                for (int e = 0; e < 4; ++e) {
                    float v = acc[i][j][e] + bv[j];
                    if (RELU) v = fmaxf(v, 0.f);
                    const int row = i * 16 + r4 + e;
                    const int col = j * 16 + fr;
                    sl[row * 64 + (col ^ ((row & 7) << 3))] = f2bf(v);
                }
        unsigned short* Cb = (unsigned short*)Cout + (size_t)bat * sC;
#pragma unroll
        for (int rr = 0; rr < 16; ++rr) {
            const int row = rr * 8 + (lane >> 3);
            const int k8  = lane & 7;
            us8 v = *(const us8*)&sl[row * 64 + ((k8 ^ (row & 7)) << 3)];
            *(us8*)&Cb[(size_t)(R0 + row) * N + C0 + k8 * 8] = v;
        }
    }
}

extern "C" void kernel_launch(void* const* d_in, const int* in_sizes, int n_in,
                              void* d_out, int out_size, void* d_ws, size_t ws_size,
                              hipStream_t stream) {
    constexpr int B = 32, N = 1024, F = 512;

    const float* x0f  = (const float*)d_in[0];
    const float* adjf = (const float*)d_in[1];
    const float* W1 = (const float*)d_in[2];
    const float* b1 = (const float*)d_in[3];
    const float* W2 = (const float*)d_in[4];
    const float* b2 = (const float*)d_in[5];
    const float* W3 = (const float*)d_in[6];
    const float* b3 = (const float*)d_in[7];

    unsigned short* ws   = (unsigned short*)d_ws;
    unsigned short* adjb = ws;                           // B*N*N bf16
    unsigned short* P0   = adjb + (size_t)B * N * N;     // B*N*F
    unsigned short* P1   = P0 + (size_t)B * N * F;
    unsigned short* PT   = P1 + (size_t)B * N * F;       // B*F*N
    unsigned short* WT1  = PT + (size_t)B * N * F;
    unsigned short* WT2  = WT1 + (size_t)F * F;
    unsigned short* WT3  = WT2 + (size_t)F * F;

    prep<<<256, 256, 0, stream>>>(W1, W2, W3, WT1, WT2, WT3);

    const int grid = 256;
    const long sX = (long)N * F;
    const long sAd = (long)N * N;

    // layer 1: fused f32-input kernels
    gemm_g1f<<<grid, 512, 0, stream>>>(WT1, x0f, PT);
    gemm_g2f<<<grid, 512, 0, stream>>>(adjf, adjb, PT, P1, b1);
    // layer 2
    gemm256<false, false><<<grid, 512, 0, stream>>>(WT2,  P1, PT, nullptr, F, N, F, 0,  sX, sX);
    gemm256<true,  false><<<grid, 512, 0, stream>>>(adjb, PT, P0, b2,      N, F, N, sAd, sX, sX);
    // layer 3 (fp32 out, no relu)
    gemm256<false, false><<<grid, 512, 0, stream>>>(WT3,  P0, PT, nullptr, F, N, F, 0,  sX, sX);
    gemm256<false, true ><<<grid, 512, 0, stream>>>(adjb, PT, (float*)d_out, b3, N, F, N, sAd, sX, sX);
}

// Round 14
// 228.521 us; speedup vs baseline: 1.1390x; 1.1390x over previous
//
#include <hip/hip_runtime.h>
#include <hip/hip_bf16.h>

// GCN: 3 x [ relu(A @ (X @ W) + b) ]  (no relu layer 3), fp32 I/O, bf16 MFMA.
// R13 = R11 (best, 231.5us) + G2f fixes: (1) adjb writeback split across the
// two blocks sharing each A-panel (4 stores/tile each, balanced) and (2) exact
// counted vmcnt ledger (16 steady / 12 at nt-2) so wb stores and next reg-loads
// never drain early. G1f / gemm256 / prep byte-identical to R11.
//   G1: T  = W^T @ X^T : gemm(A=WT [F][F], BT=X [N][F]) -> T [F][N]
//   G2: X' = adj @ T^T : gemm(A=adj [N][N], BT=T [F][N]) -> X' [N][F] (+b,relu)

typedef __attribute__((ext_vector_type(8))) short bf16x8s;
typedef __attribute__((ext_vector_type(4))) float f32x4;
typedef __attribute__((ext_vector_type(4))) unsigned short us4;
typedef __attribute__((ext_vector_type(8))) unsigned short us8;

__device__ __forceinline__ unsigned short f2bf(float f) {
    unsigned u = __builtin_bit_cast(unsigned, f);
    u += 0x7fffu + ((u >> 16) & 1u);          // RNE
    return (unsigned short)(u >> 16);
}

__device__ __forceinline__ us8 pack8(float4 a, float4 b) {
    us8 o;
    o[0] = f2bf(a.x); o[1] = f2bf(a.y); o[2] = f2bf(a.z); o[3] = f2bf(a.w);
    o[4] = f2bf(b.x); o[5] = f2bf(b.y); o[6] = f2bf(b.z); o[7] = f2bf(b.w);
    return o;
}

__device__ __forceinline__ void async16(const unsigned short* g, unsigned short* l) {
    __builtin_amdgcn_global_load_lds(
        (const __attribute__((address_space(1))) unsigned int*)g,
        (__attribute__((address_space(3))) unsigned int*)l, 16, 0, 0);
}

#define MFMA_(d, va, vb) d = __builtin_amdgcn_mfma_f32_16x16x32_bf16(va, vb, d, 0, 0, 0)

// -------- prep: three W transposes only (3 MB) --------
__global__ void prep(const float* __restrict__ W1, const float* __restrict__ W2,
                     const float* __restrict__ W3, unsigned short* __restrict__ WT1,
                     unsigned short* __restrict__ WT2, unsigned short* __restrict__ WT3) {
    constexpr int F = 512;
    const long FF = (long)F * F;
    const long S = (long)gridDim.x * 256;
    for (long k = (long)blockIdx.x * 256 + threadIdx.x; k < 3 * FF; k += S) {
        int w = (int)(k / FF);
        long idx = k % FF;
        int r = (int)(idx % F);
        int c = (int)(idx / F);
        const float* W = (w == 0) ? W1 : (w == 1) ? W2 : W3;
        unsigned short* WT = (w == 0) ? WT1 : (w == 1) ? WT2 : WT3;
        WT[idx] = f2bf(W[(size_t)r * F + c]);
    }
}

// ================= fused G1 layer-1: PT = WT1 @ X0^T (X0 = f32) =============
__global__ __launch_bounds__(512, 2)
void gemm_g1f(const unsigned short* __restrict__ WT,   // [512][512] bf16
              const float* __restrict__ X0,            // [32][1024][512] f32
              unsigned short* __restrict__ PT)         // [32][512][1024] bf16
{
    constexpr int K = 512, NN = 1024;
    constexpr int nt = K >> 6;                          // 8
    __shared__ unsigned short Lraw[65536];              // A dbuf 64KB | B dbuf 64KB

    const int t = threadIdx.x, lane = t & 63, wv = t >> 6;
    const int wm = wv >> 2, wn = wv & 3;
    const int fr = lane & 15, fk = (lane >> 4) * 8, r4 = (lane >> 4) * 4;
    const int lb = ((int)blockIdx.x & 7) * 32 + ((int)blockIdx.x >> 3);
    const int bat = lb >> 3, tt = lb & 7;
    const int m0 = (tt >> 2) << 8, n0 = (tt & 3) << 8;  // 2 M-tiles x 4 N-tiles

    const unsigned short* Ab = WT + (size_t)m0 * K;
    const float* Bb = X0 + (size_t)bat * NN * K + (size_t)n0 * K;

    int srow[2], scol[2], lo[2];
#pragma unroll
    for (int r = 0; r < 2; ++r) {
        int c   = r * 512 + t;
        srow[r] = c >> 3;
        scol[r] = ((c & 7) * 8) ^ ((srow[r] & 7) << 3);
        lo[r]   = c * 8;
    }

    auto stageA = [&](int kt, int h) {
        unsigned short* base = Lraw + (kt & 1) * 16384;
#pragma unroll
        for (int r = 0; r < 2; ++r)
            async16(Ab + (size_t)(h * 128 + srow[r]) * K + kt * 64 + scol[r],
                    base + h * 8192 + lo[r]);
    };
    auto rdA = [&](int buf, int mf, int kkj) -> bf16x8s {
        int row = wm * 128 + mf * 16 + fr;
        int e   = (kkj * 32 + fk) ^ ((row & 7) << 3);
        return *(const bf16x8s*)&Lraw[buf * 16384 + row * 64 + e];
    };
    auto rdB = [&](int buf, int nf, int kkj) -> bf16x8s {
        int row = wn * 64 + nf * 16 + fr;
        int e   = (kkj * 32 + fk) ^ ((row & 7) << 3);
        return *(const bf16x8s*)&Lraw[32768 + buf * 16384 + row * 64 + e];
    };

    float4 fa[4], fb[4];
    auto loadB = [&](int kt) {
#pragma unroll
        for (int h = 0; h < 2; ++h)
#pragma unroll
            for (int r = 0; r < 2; ++r) {
                const float* p = Bb + (size_t)(h * 128 + srow[r]) * K + kt * 64 + scol[r];
                fa[h * 2 + r] = *(const float4*)p;
                fb[h * 2 + r] = *(const float4*)(p + 4);
            }
    };
    auto writeB = [&](int buf) {
#pragma unroll
        for (int h = 0; h < 2; ++h)
#pragma unroll
            for (int r = 0; r < 2; ++r)
                *(us8*)&Lraw[32768 + buf * 16384 + h * 8192 + lo[r]] =
                    pack8(fa[h * 2 + r], fb[h * 2 + r]);
    };

    f32x4 acc[8][4];
#pragma unroll
    for (int i = 0; i < 8; ++i)
#pragma unroll
        for (int j = 0; j < 4; ++j) acc[i][j] = f32x4{0.f, 0.f, 0.f, 0.f};
    bf16x8s aP[4], aB[4], aC[4], bX[4], bY[4];

    loadB(0);
    stageA(0, 0); stageA(0, 1);
    writeB(0);
    loadB(1);
    asm volatile("s_waitcnt vmcnt(8)" ::: "memory");
    __syncthreads();
#pragma unroll
    for (int m = 0; m < 4; ++m) aP[m] = rdA(0, m, 0);
#pragma unroll
    for (int n = 0; n < 4; ++n) bX[n] = rdB(0, n, 0);

    for (int it = 0; it < nt; ++it) {
        const int cur = it & 1, nxt = cur ^ 1;
        const bool m1 = it + 1 < nt, m2 = it + 2 < nt;

        __builtin_amdgcn_s_barrier();                       // ph0
#pragma unroll
        for (int m = 0; m < 4; ++m) aB[m] = rdA(cur, m + 4, 0);
        if (m1) { stageA(it + 1, 0); stageA(it + 1, 1); }
        __builtin_amdgcn_s_setprio(1);
#pragma unroll
        for (int m = 0; m < 4; ++m)
#pragma unroll
            for (int n = 0; n < 4; ++n) MFMA_(acc[m][n], aP[m], bX[n]);
        __builtin_amdgcn_s_setprio(0);

        __builtin_amdgcn_s_barrier();                       // ph1
#pragma unroll
        for (int m = 0; m < 4; ++m) aC[m] = rdA(cur, m, 1);
#pragma unroll
        for (int n = 0; n < 4; ++n) bY[n] = rdB(cur, n, 1);
        __builtin_amdgcn_s_setprio(1);
#pragma unroll
        for (int m = 0; m < 4; ++m)
#pragma unroll
            for (int n = 0; n < 4; ++n) MFMA_(acc[m + 4][n], aB[m], bX[n]);
        __builtin_amdgcn_s_setprio(0);

        __builtin_amdgcn_s_barrier();                       // ph2
#pragma unroll
        for (int m = 0; m < 4; ++m) aB[m] = rdA(cur, m + 4, 1);
        if (m1) writeB(nxt);
        if (m2) loadB(it + 2);
        __builtin_amdgcn_s_setprio(1);
#pragma unroll
        for (int m = 0; m < 4; ++m)
#pragma unroll
            for (int n = 0; n < 4; ++n) MFMA_(acc[m][n], aC[m], bY[n]);
        __builtin_amdgcn_s_setprio(0);

        if (m1) {                                           // ph3
            if (m2) asm volatile("s_waitcnt vmcnt(8) lgkmcnt(0)" ::: "memory");
            else    asm volatile("s_waitcnt vmcnt(0) lgkmcnt(0)" ::: "memory");
            __builtin_amdgcn_s_barrier();
#pragma unroll
            for (int m = 0; m < 4; ++m) aP[m] = rdA(nxt, m, 0);
#pragma unroll
            for (int n = 0; n < 4; ++n) bX[n] = rdB(nxt, n, 0);
        }
        __builtin_amdgcn_s_setprio(1);
#pragma unroll
        for (int m = 0; m < 4; ++m)
#pragma unroll
            for (int n = 0; n < 4; ++n) MFMA_(acc[m + 4][n], aB[m], bY[n]);
        __builtin_amdgcn_s_setprio(0);
    }

    __syncthreads();
    const int R0 = m0 + wm * 128;
    const int C0 = n0 + wn * 64;
    unsigned short* sl = Lraw + wv * 8192;
#pragma unroll
    for (int i = 0; i < 8; ++i)
#pragma unroll
        for (int j = 0; j < 4; ++j)
#pragma unroll
            for (int e = 0; e < 4; ++e) {
                const int row = i * 16 + r4 + e;
                const int col = j * 16 + fr;
                sl[row * 64 + (col ^ ((row & 7) << 3))] = f2bf(acc[i][j][e]);
            }
    unsigned short* Cb = PT + (size_t)bat * 512 * 1024;
#pragma unroll
    for (int rr = 0; rr < 16; ++rr) {
        const int row = rr * 8 + (lane >> 3);
        const int k8  = lane & 7;
        us8 v = *(const us8*)&sl[row * 64 + ((k8 ^ (row & 7)) << 3)];
        *(us8*)&Cb[(size_t)(R0 + row) * NN + C0 + k8 * 8] = v;
    }
}

// ====== fused G2 layer-1: P1 = relu(adj @ PT^T + b1), adj f32 + split wb ====
// B (PT) triple-buffered, staged 2 ahead; exact counted vmcnt (16/12).
// Writeback split: n0==0 block writes rows 0-127 of its A-panel, n0==256
// block writes rows 128-255 (A-panels are shared pairwise) -> 4 stores/tile.
__global__ __launch_bounds__(512, 2)
void gemm_g2f(const float* __restrict__ ADJ,            // [32][1024][1024] f32
              unsigned short* __restrict__ adjb,        // bf16 out (plain layout)
              const unsigned short* __restrict__ PT,    // [32][512][1024] bf16
              unsigned short* __restrict__ P1,          // [32][1024][512] bf16
              const float* __restrict__ bias)
{
    constexpr int K = 1024, NN = 512;
    constexpr int nt = K >> 6;                          // 16
    // 160 KiB: A dbuf 2x16384 | B tripbuf 3x16384 (elems)
    __shared__ unsigned short Lraw[81920];

    const int t = threadIdx.x, lane = t & 63, wv = t >> 6;
    const int wm = wv >> 2, wn = wv & 3;
    const int fr = lane & 15, fk = (lane >> 4) * 8, r4 = (lane >> 4) * 4;
    const int lb = ((int)blockIdx.x & 7) * 32 + ((int)blockIdx.x >> 3);
    const int bat = lb >> 3, tt = lb & 7;
    const int m0 = (tt >> 1) << 8, n0 = (tt & 1) << 8;  // 4 M-tiles x 2 N-tiles
    const int wbh = (n0 == 0) ? 0 : 1;                  // which A half this block writes back

    const float* Afb = ADJ + (size_t)bat * K * K + (size_t)m0 * K;
    unsigned short* Awb = adjb + (size_t)bat * K * K + (size_t)m0 * K;
    const unsigned short* Bb = PT + (size_t)bat * NN * K + (size_t)n0 * K;

    int srow[2], scol[2], lo[2];
#pragma unroll
    for (int r = 0; r < 2; ++r) {
        int c   = r * 512 + t;
        srow[r] = c >> 3;
        scol[r] = ((c & 7) * 8) ^ ((srow[r] & 7) << 3);
        lo[r]   = c * 8;
    }

    auto stageB = [&](int buf, int kt) {                // both halves, 4 asyncs
        unsigned short* base = Lraw + 32768 + buf * 16384;
#pragma unroll
        for (int h = 0; h < 2; ++h)
#pragma unroll
            for (int r = 0; r < 2; ++r)
                async16(Bb + (size_t)(h * 128 + srow[r]) * K + kt * 64 + scol[r],
                        base + h * 8192 + lo[r]);
    };
    auto rdA = [&](int buf, int mf, int kkj) -> bf16x8s {
        int row = wm * 128 + mf * 16 + fr;
        int e   = (kkj * 32 + fk) ^ ((row & 7) << 3);
        return *(const bf16x8s*)&Lraw[buf * 16384 + row * 64 + e];
    };
    auto rdB = [&](int buf, int nf, int kkj) -> bf16x8s {
        int row = wn * 64 + nf * 16 + fr;
        int e   = (kkj * 32 + fk) ^ ((row & 7) << 3);
        return *(const bf16x8s*)&Lraw[32768 + buf * 16384 + row * 64 + e];
    };

    float4 fa[4], fb[4];
    auto loadA = [&](int kt) {                          // 8 f32x4 reg loads
#pragma unroll
        for (int h = 0; h < 2; ++h)
#pragma unroll
            for (int r = 0; r < 2; ++r) {
                const float* p = Afb + (size_t)(h * 128 + srow[r]) * K + kt * 64 + scol[r];
                fa[h * 2 + r] = *(const float4*)p;
                fb[h * 2 + r] = *(const float4*)(p + 4);
            }
    };
    auto flushA = [&](int buf, int kt) {                // cvt + ds_write + split wb (4 stores)
#pragma unroll
        for (int h = 0; h < 2; ++h)
#pragma unroll
            for (int r = 0; r < 2; ++r) {
                us8 v = pack8(fa[h * 2 + r], fb[h * 2 + r]);
                *(us8*)&Lraw[buf * 16384 + h * 8192 + lo[r]] = v;
                if (h == wbh)
                    *(us8*)&Awb[(size_t)(h * 128 + srow[r]) * K + kt * 64 + scol[r]] = v;
            }
    };

    f32x4 acc[8][4];
#pragma unroll
    for (int i = 0; i < 8; ++i)
#pragma unroll
        for (int j = 0; j < 4; ++j) acc[i][j] = f32x4{0.f, 0.f, 0.f, 0.f};
    bf16x8s aP[4], aB[4], aC[4], bX[4], bY[4];

    // prologue (ordered so vmcnt(16) leaves wb+loadA(1)+stageB(1) in flight):
    loadA(0);                       // 8
    stageB(0, 0);                   // 4
    flushA(0, 0);                   // ds_writes + 4 wb stores (reg-dep drains loadA(0))
    stageB(1, 1);                   // 4
    loadA(1);                       // 8
    // need stageB(0) landed; newer: wb4? (wb is older than stageB(1)) -> after
    // stageB(0): wb 4 + stageB(1) 4 + loadA(1) 8 = 16
    asm volatile("s_waitcnt vmcnt(16)" ::: "memory");
    __syncthreads();                // drains lgkm (ds_writes visible)
#pragma unroll
    for (int m = 0; m < 4; ++m) aP[m] = rdA(0, m, 0);
#pragma unroll
    for (int n = 0; n < 4; ++n) bX[n] = rdB(0, n, 0);

    int bc = 0;                     // B buffer of current tile
    for (int it = 0; it < nt; ++it) {
        const int cur = it & 1, nxt = cur ^ 1;
        const int bn1 = (bc == 2) ? 0 : bc + 1;
        const int bn2 = (bn1 == 2) ? 0 : bn1 + 1;
        const bool m1 = it + 1 < nt, m2 = it + 2 < nt;

        __builtin_amdgcn_s_barrier();                       // ph0
#pragma unroll
        for (int m = 0; m < 4; ++m) aB[m] = rdA(cur, m + 4, 0);
        __builtin_amdgcn_s_setprio(1);
#pragma unroll
        for (int m = 0; m < 4; ++m)
#pragma unroll
            for (int n = 0; n < 4; ++n) MFMA_(acc[m][n], aP[m], bX[n]);
        __builtin_amdgcn_s_setprio(0);

        __builtin_amdgcn_s_barrier();                       // ph1
#pragma unroll
        for (int m = 0; m < 4; ++m) aC[m] = rdA(cur, m, 1);
#pragma unroll
        for (int n = 0; n < 4; ++n) bY[n] = rdB(bc, n, 1);
        __builtin_amdgcn_s_setprio(1);
#pragma unroll
        for (int m = 0; m < 4; ++m)
#pragma unroll
            for (int n = 0; n < 4; ++n) MFMA_(acc[m + 4][n], aB[m], bX[n]);
        __builtin_amdgcn_s_setprio(0);

        __builtin_amdgcn_s_barrier();                       // ph2
#pragma unroll
        for (int m = 0; m < 4; ++m) aB[m] = rdA(cur, m + 4, 1);
        if (m1) flushA(nxt, it + 1);                        // ds_writes + 4 wb stores
        if (m2) stageB(bn2, it + 2);                        // 4 asyncs (newest)
        __builtin_amdgcn_s_setprio(1);
#pragma unroll
        for (int m = 0; m < 4; ++m)
#pragma unroll
            for (int n = 0; n < 4; ++n) MFMA_(acc[m][n], aC[m], bY[n]);
        __builtin_amdgcn_s_setprio(0);

        if (m1) {                                           // ph3
            // need stageB(it+1) landed (issued ph2 of it-1 / prologue).
            // newer: loadA(it+1) 8 + wb 4 + stageB(it+2) 4 = 16  (m2)
            //        loadA(it+1) 8 + wb 4                 = 12  (!m2)
            if (m2) asm volatile("s_waitcnt vmcnt(16) lgkmcnt(0)" ::: "memory");
            else    asm volatile("s_waitcnt vmcnt(12) lgkmcnt(0)" ::: "memory");
            __builtin_amdgcn_s_barrier();
#pragma unroll
            for (int m = 0; m < 4; ++m) aP[m] = rdA(nxt, m, 0);
#pragma unroll
            for (int n = 0; n < 4; ++n) bX[n] = rdB(bn1, n, 0);
            if (m2) loadA(it + 2);                          // 8 f32 loads
        }
        __builtin_amdgcn_s_setprio(1);
#pragma unroll
        for (int m = 0; m < 4; ++m)
#pragma unroll
            for (int n = 0; n < 4; ++n) MFMA_(acc[m + 4][n], aB[m], bY[n]);
        __builtin_amdgcn_s_setprio(0);
        bc = bn1;
    }

    __syncthreads();
    // epilogue: bias + relu, LDS bounce, P1 row-major [1024][512]
    const int R0 = m0 + wm * 128;
    const int C0 = n0 + wn * 64;
    float bv[4];
#pragma unroll
    for (int j = 0; j < 4; ++j) bv[j] = bias[C0 + j * 16 + fr];
    unsigned short* sl = Lraw + wv * 8192;
#pragma unroll
    for (int i = 0; i < 8; ++i)
#pragma unroll
        for (int j = 0; j < 4; ++j)
#pragma unroll
            for (int e = 0; e < 4; ++e) {
                const int row = i * 16 + r4 + e;
                const int col = j * 16 + fr;
                sl[row * 64 + (col ^ ((row & 7) << 3))] =
                    f2bf(fmaxf(acc[i][j][e] + bv[j], 0.f));
            }
    unsigned short* Cb = P1 + (size_t)bat * 1024 * 512;
#pragma unroll
    for (int rr = 0; rr < 16; ++rr) {
        const int row = rr * 8 + (lane >> 3);
        const int k8  = lane & 7;
        us8 v = *(const us8*)&sl[row * 64 + ((k8 ^ (row & 7)) << 3)];
        *(us8*)&Cb[(size_t)(R0 + row) * NN + C0 + k8 * 8] = v;
    }
}

// ================= R8 core (unchanged) for the 4 bf16 GEMMs =================
template<bool RELU, bool OUT_F32>
__global__ __launch_bounds__(512, 2)
void gemm256(const unsigned short* __restrict__ A,
             const unsigned short* __restrict__ BT,
             void* __restrict__ Cout,
             const float* __restrict__ bias,
             int M, int N, int K,
             long sA, long sBT, long sC)
{
    __shared__ unsigned short Lraw[81920];

    const int t    = threadIdx.x;
    const int lane = t & 63;
    const int wv   = t >> 6;
    const int wm   = wv >> 2;
    const int wn   = wv & 3;
    const int fr   = lane & 15;
    const int fk   = (lane >> 4) * 8;
    const int r4   = (lane >> 4) * 4;

    const int tilesN = N >> 8;
    const int bpb    = (M >> 8) * tilesN;
    const int cpx = gridDim.x >> 3;
    const int lb  = (blockIdx.x & 7) * cpx + (blockIdx.x >> 3);
    const int bat = lb / bpb;
    const int tt  = lb % bpb;
    const int m0  = (tt / tilesN) << 8;
    const int n0  = (tt % tilesN) << 8;

    const unsigned short* Ab = A  + (size_t)bat * sA  + (size_t)m0 * K;
    const unsigned short* Bb = BT + (size_t)bat * sBT + (size_t)n0 * K;

    int srow[2], scol[2], lo[2];
#pragma unroll
    for (int r = 0; r < 2; ++r) {
        int c   = r * 512 + t;
        srow[r] = c >> 3;
        scol[r] = ((c & 7) * 8) ^ ((srow[r] & 7) << 3);
        lo[r]   = c * 8;
    }

    auto stageA = [&](int kt, int h) {
        unsigned short* base = Lraw + (kt & 1) * 16384;
#pragma unroll
        for (int r = 0; r < 2; ++r)
            async16(Ab + (size_t)(h * 128 + srow[r]) * K + kt * 64 + scol[r],
                    base + h * 8192 + lo[r]);
    };
    auto stageB = [&](int buf, int kt) {
        unsigned short* base = Lraw + 32768 + buf * 16384;
#pragma unroll
        for (int h = 0; h < 2; ++h)
#pragma unroll
            for (int r = 0; r < 2; ++r)
                async16(Bb + (size_t)(h * 128 + srow[r]) * K + kt * 64 + scol[r],
                        base + h * 8192 + lo[r]);
    };
    auto rdA = [&](int buf, int mf, int kkj) -> bf16x8s {
        int row = wm * 128 + mf * 16 + fr;
        int e   = (kkj * 32 + fk) ^ ((row & 7) << 3);
        return *(const bf16x8s*)&Lraw[buf * 16384 + row * 64 + e];
    };
    auto rdB = [&](int buf, int nf, int kkj) -> bf16x8s {
        int row = wn * 64 + nf * 16 + fr;
        int e   = (kkj * 32 + fk) ^ ((row & 7) << 3);
        return *(const bf16x8s*)&Lraw[32768 + buf * 16384 + row * 64 + e];
    };

    const int nt = K >> 6;

    f32x4 acc[8][4];
#pragma unroll
    for (int i = 0; i < 8; ++i)
#pragma unroll
        for (int j = 0; j < 4; ++j) acc[i][j] = f32x4{0.f, 0.f, 0.f, 0.f};

    bf16x8s aP[4], aB[4], aC[4], bX[4], bY[4];

    stageA(0, 0); stageA(0, 1);
    stageB(0, 0);
    if (nt > 1) {
        stageB(1, 1);
        asm volatile("s_waitcnt vmcnt(4)" ::: "memory");
    } else {
        asm volatile("s_waitcnt vmcnt(0)" ::: "memory");
    }
    __builtin_amdgcn_s_barrier();
#pragma unroll
    for (int m = 0; m < 4; ++m) aP[m] = rdA(0, m, 0);
#pragma unroll
    for (int n = 0; n < 4; ++n) bX[n] = rdB(0, n, 0);

    int bc = 0;
    for (int it = 0; it < nt; ++it) {
        const int cur = it & 1;
        const int bn1 = (bc == 2) ? 0 : bc + 1;
        const int bn2 = (bn1 == 2) ? 0 : bn1 + 1;
        const bool m1 = (it + 1 < nt), m2 = (it + 2 < nt);

        __builtin_amdgcn_s_barrier();
#pragma unroll
        for (int m = 0; m < 4; ++m) aB[m] = rdA(cur, m + 4, 0);
        if (m1) stageA(it + 1, 0);
        __builtin_amdgcn_s_setprio(1);
#pragma unroll
        for (int m = 0; m < 4; ++m)
#pragma unroll
            for (int n = 0; n < 4; ++n) MFMA_(acc[m][n], aP[m], bX[n]);
        __builtin_amdgcn_s_setprio(0);

        __builtin_amdgcn_s_barrier();
#pragma unroll
        for (int m = 0; m < 4; ++m) aC[m] = rdA(cur, m, 1);
#pragma unroll
        for (int n = 0; n < 4; ++n) bY[n] = rdB(bc, n, 1);
        if (m1) stageA(it + 1, 1);
        __builtin_amdgcn_s_setprio(1);
#pragma unroll
        for (int m = 0; m < 4; ++m)
#pragma unroll
            for (int n = 0; n < 4; ++n) MFMA_(acc[m + 4][n], aB[m], bX[n]);
        __builtin_amdgcn_s_setprio(0);

        __builtin_amdgcn_s_barrier();
#pragma unroll
        for (int m = 0; m < 4; ++m) aB[m] = rdA(cur, m + 4, 1);
        if (m2) stageB(bn2, it + 2);
        __builtin_amdgcn_s_setprio(1);
#pragma unroll
        for (int m = 0; m < 4; ++m)
#pragma unroll
            for (int n = 0; n < 4; ++n) MFMA_(acc[m][n], aC[m], bY[n]);
        __builtin_amdgcn_s_setprio(0);

        if (m1) {
            if (m2) asm volatile("s_waitcnt vmcnt(4)" ::: "memory");
            else    asm volatile("s_waitcnt vmcnt(0)" ::: "memory");
            __builtin_amdgcn_s_barrier();
#pragma unroll
            for (int m = 0; m < 4; ++m) aP[m] = rdA(cur ^ 1, m, 0);
#pragma unroll
            for (int n = 0; n < 4; ++n) bX[n] = rdB(bn1, n, 0);
        }
        __builtin_amdgcn_s_setprio(1);
#pragma unroll
        for (int m = 0; m < 4; ++m)
#pragma unroll
            for (int n = 0; n < 4; ++n) MFMA_(acc[m + 4][n], aB[m], bY[n]);
        __builtin_amdgcn_s_setprio(0);
        bc = bn1;
    }

    __syncthreads();

    const int R0 = m0 + wm * 128;
    const int C0 = n0 + wn * 64;
    float bv[4];
#pragma unroll
    for (int j = 0; j < 4; ++j)
        bv[j] = bias ? bias[C0 + j * 16 + fr] : 0.f;

    if (OUT_F32) {
        float* Cb = (float*)Cout + (size_t)bat * sC;
#pragma unroll
        for (int j = 0; j < 4; ++j)
#pragma unroll
            for (int i = 0; i < 8; ++i)
#pragma unroll
                for (int e = 0; e < 4; ++e) {
                    float v = acc[i][j][e] + bv[j];
                    if (RELU) v = fmaxf(v, 0.f);
                    Cb[(size_t)(R0 + i * 16 + r4 + e) * N + C0 + j * 16 + fr] = v;
                }
    } else {
        unsigned short* sl = Lraw + wv * 8192;
#pragma unroll
        for (int i = 0; i < 8; ++i)
#pragma unroll
            for (int j = 0; j < 4; ++j)
#pragma unroll
                for (int e = 0; e < 4; ++e) {
                    float v = acc[i][j][e] + bv[j];
                    if (RELU) v = fmaxf(v, 0.f);
                    const int row = i * 16 + r4 + e;
                    const int col = j * 16 + fr;
                    sl[row * 64 + (col ^ ((row & 7) << 3))] = f2bf(v);
                }
        unsigned short* Cb = (unsigned short*)Cout + (size_t)bat * sC;
#pragma unroll
        for (int rr = 0; rr < 16; ++rr) {
            const int row = rr * 8 + (lane >> 3);
            const int k8  = lane & 7;
            us8 v = *(const us8*)&sl[row * 64 + ((k8 ^ (row & 7)) << 3)];
            *(us8*)&Cb[(size_t)(R0 + row) * N + C0 + k8 * 8] = v;
        }
    }
}

extern "C" void kernel_launch(void* const* d_in, const int* in_sizes, int n_in,
                              void* d_out, int out_size, void* d_ws, size_t ws_size,
                              hipStream_t stream) {
    constexpr int B = 32, N = 1024, F = 512;

    const float* x0f  = (const float*)d_in[0];
    const float* adjf = (const float*)d_in[1];
    const float* W1 = (const float*)d_in[2];
    const float* b1 = (const float*)d_in[3];
    const float* W2 = (const float*)d_in[4];
    const float* b2 = (const float*)d_in[5];
    const float* W3 = (const float*)d_in[6];
    const float* b3 = (const float*)d_in[7];

    unsigned short* ws   = (unsigned short*)d_ws;
    unsigned short* adjb = ws;                           // B*N*N bf16
    unsigned short* P0   = adjb + (size_t)B * N * N;     // B*N*F
    unsigned short* P1   = P0 + (size_t)B * N * F;
    unsigned short* PT   = P1 + (size_t)B * N * F;       // B*F*N
    unsigned short* WT1  = PT + (size_t)B * N * F;
    unsigned short* WT2  = WT1 + (size_t)F * F;
    unsigned short* WT3  = WT2 + (size_t)F * F;

    prep<<<256, 256, 0, stream>>>(W1, W2, W3, WT1, WT2, WT3);

    const int grid = 256;
    const long sX = (long)N * F;
    const long sAd = (long)N * N;

    // layer 1: fused f32-input kernels
    gemm_g1f<<<grid, 512, 0, stream>>>(WT1, x0f, PT);
    gemm_g2f<<<grid, 512, 0, stream>>>(adjf, adjb, PT, P1, b1);
    // layer 2
    gemm256<false, false><<<grid, 512, 0, stream>>>(WT2,  P1, PT, nullptr, F, N, F, 0,  sX, sX);
    gemm256<true,  false><<<grid, 512, 0, stream>>>(adjb, PT, P0, b2,      N, F, N, sAd, sX, sX);
    // layer 3 (fp32 out, no relu)
    gemm256<false, false><<<grid, 512, 0, stream>>>(WT3,  P0, PT, nullptr, F, N, F, 0,  sX, sX);
    gemm256<false, true ><<<grid, 512, 0, stream>>>(adjb, PT, (float*)d_out, b3, N, F, N, sAd, sX, sX);
}